// Round 9
// baseline (101.018 us; speedup 1.0000x reference)
//
#include <hip/hip_runtime.h>
#include <math.h>

// InputMPNN on MI355X — v6: fused kernel re-tiled for phase overlap.
// (resubmit; R8 was an infra acquisition timeout — kernel never ran)
// v2/v4/v5 all ~92 us despite different structures; common trait = 1 block/CU
// (LDS >= 97KB) with serialized Q-build -> MFMA -> mlp phases. v6: block =
// (b, 2 rows), 1024 blocks, 256 thr, 48 KB LDS -> 3 blocks/CU, 12 waves/CU:
// independent blocks overlap phases (m114 MFMA||VALU co-scheduling).
// bf16 operands PRE-SWIZZLED: elem k -> k ^ ((row&7)<<3) (byte ^ ((row&7)<<4)).

typedef __attribute__((ext_vector_type(8))) short bf16x8;
typedef __attribute__((ext_vector_type(4))) float f32x4;
typedef unsigned short u16;

#define BB 8
#define NN 256
#define CC 128

__device__ __forceinline__ u16 f2bf(float f) {
    union { float f; unsigned int u; } v; v.f = f;
    unsigned int u = v.u;
    return (u16)((u + 0x7FFFu + ((u >> 16) & 1u)) >> 16);   // RNE
}

#define MFMA(a, b, c) __builtin_amdgcn_mfma_f32_16x16x32_bf16((a), (b), (c), 0, 0, 0)

// ---------------- prep: transposes + bf16 converts (all pre-swizzled) -------
__global__ __launch_bounds__(256) void prep_kernel(
    const float* __restrict__ features, const float* __restrict__ W1,
    const float* __restrict__ W2, u16* __restrict__ Ft,
    u16* __restrict__ W1t, u16* __restrict__ W2t)
{
    __shared__ float S[64][65];
    const int blk = blockIdx.x, t = threadIdx.x;
    if (blk < 64) {                    // Ft[b][c][x^] = features[b][x][c]
        const int b = blk >> 3, tl = blk & 7, c0 = (tl >> 2) * 64, x0 = (tl & 3) * 64;
        const int j = t & 63, ri = t >> 6;
#pragma unroll
        for (int rr = 0; rr < 16; ++rr) {
            int xl = rr * 4 + ri;
            S[j][xl] = features[(size_t)(b * NN + x0 + xl) * CC + c0 + j];
        }
        __syncthreads();
#pragma unroll
        for (int rr = 0; rr < 16; ++rr) {
            int cl = rr * 4 + ri;
            int c = c0 + cl, x = x0 + j;
            Ft[(size_t)(b * CC + c) * NN + (x ^ ((c & 7) << 3))] = f2bf(S[cl][j]);
        }
    } else {                           // W1t/W2t[n][k^] = W[k][n]
        const int isW2 = (blk >= 80), tl = (blk - 64) & 15;
        const int n0 = (tl >> 2) * 64, k0 = (tl & 3) * 64;
        const float* W = isW2 ? W2 : W1;
        u16* Wt = isW2 ? W2t : W1t;
        const int j = t & 63, ri = t >> 6;
#pragma unroll
        for (int rr = 0; rr < 16; ++rr) {
            int kl = rr * 4 + ri;
            S[j][kl] = W[(size_t)(k0 + kl) * 256 + n0 + j];
        }
        __syncthreads();
#pragma unroll
        for (int rr = 0; rr < 16; ++rr) {
            int nl = rr * 4 + ri;
            int n = n0 + nl, k = k0 + j;
            Wt[(size_t)n * 256 + (k ^ ((n & 7) << 3))] = f2bf(S[nl][j]);
        }
    }
}

// ---------------- fused v6: (b, 2 rows) per block, 3 blocks/CU --------------
__global__ __launch_bounds__(256, 3) void fused_kernel(
    const float* __restrict__ norms, const float* __restrict__ features,
    const u16* __restrict__ Ft,
    const float* __restrict__ rad_W, const float* __restrict__ rad_b,
    const u16* __restrict__ W1t, const float* __restrict__ b1,
    const u16* __restrict__ W2t, const float* __restrict__ b2,
    float* __restrict__ out)
{
    __shared__ __align__(16) char Q[2][16384];     // 32 KB: 2 row-tiles
    __shared__ __align__(16) u16 X[16][256];       // 8 KB (rows 2..15 pad)
    __shared__ __align__(16) u16 H[16][256];       // 8 KB

    // XCD swizzle: 128 consecutive blocks per XCD share b -> Ft[b] L2-hot
    const int bid = blockIdx.x;
    const int swz = (bid & 7) * 128 + (bid >> 3);
    const int b = swz >> 7, r0 = (swz & 127) * 2;

    const int t = threadIdx.x, w = t >> 6, lane = t & 63;
    const int g = lane >> 4, rA = lane & 15;

    // ---- F K-slices into registers (wave w owns c in [32w,32w+32)) ----
    bf16x8 Freg[8][2];
    {
        const u16* fb = Ft + (size_t)b * 32768;
#pragma unroll
        for (int kq = 0; kq < 8; ++kq)
#pragma unroll
            for (int n = 0; n < 2; ++n) {
                int c = 32 * w + 16 * n + rA;
                int xb = 32 * kq + 8 * g;
                Freg[kq][n] = *(const bf16x8*)(fb + (size_t)c * 256 + (xb ^ ((c & 7) << 3)));
            }
    }

    // ---- W' into registers ----
    float Wreg[2][2][4];
#pragma unroll
    for (int m = 0; m < 2; ++m)
#pragma unroll
        for (int n = 0; n < 2; ++n)
#pragma unroll
            for (int r = 0; r < 4; ++r) {
                const int kb = 16 * m + 4 * g + r;
                const int c = 32 * w + 16 * n + rA;
                float v;
                if (kb < 28)       v = rad_W[(size_t)(kb + 4) * CC + c];
                else if (kb == 28) v = rad_b[c];
                else               v = 0.f;
                Wreg[m][n][r] = v;
            }

    // ---- zero Q rows 29..31 of both tiles ----
#pragma unroll
    for (int i = 0; i < 3; ++i) {
        int idx = t + i * 256;                     // 768 u32 = 2 x 3 x 128
        int tile = idx / 384, rm = idx - tile * 384;
        *(unsigned int*)(Q[tile] + 29 * 512 + rm * 4) = 0u;
    }

    // ---- build Q: thread t = neighbor x, both row-tiles ----
#pragma unroll
    for (int ia = 0; ia < 2; ++ia) {
        const float r_ = norms[((size_t)(b * NN + r0 + ia)) * NN + t];
        const float ir = 1.0f / r_;
        float s1, c1v;
        __sincosf(6.28318530717958647692f * r_, &s1, &c1v);
        const float s2 = 2.0f * s1 * c1v, c2 = c1v * c1v - s1 * s1;
        const float s3 = s1 * c2 + c1v * s2, c3 = c1v * c2 - s1 * s2;
        float cut = 0.0f;
        if (r_ < 1.73f) cut = 1.0f / (1.0f + __expf((r_ - 1.73f) * 5.0f));
        const float tv[7] = { s1, s2, s3, 1.0f, c1v, c2, c3 };
        const float po[4] = { cut, cut * ir, cut * ir * ir, cut * ir * ir * ir };
        char* qn = Q[ia];
#pragma unroll
        for (int i = 0; i < 7; ++i)
#pragma unroll
            for (int pw = 0; pw < 4; ++pw) {
                int kb = i * 4 + pw;
                *(u16*)(qn + kb * 512 + ((2 * t) ^ ((kb & 7) << 4))) =
                    f2bf(tv[i] * po[pw]);
            }
        *(u16*)(qn + 28 * 512 + ((2 * t) ^ ((28 & 7) << 4))) = f2bf(cut);
    }

    // ---- features -> X upper half (k = 128+c) ----
    {
        int row = t >> 7, c = t & 127;             // 256 = 2 rows x 128 c
        float v = features[(size_t)(b * NN + r0 + row) * CC + c];
        X[row][(128 + c) ^ ((row & 7) << 3)] = f2bf(v);
    }
    __syncthreads();

    // ---- fmp MFMA + register epilogue -> X lower half ----
#pragma unroll 1
    for (int ia = 0; ia < 2; ++ia) {
        const char* q = Q[ia];
        f32x4 acc[2][2] = {};
#pragma unroll
        for (int kq = 0; kq < 8; ++kq) {
            const int inner = (kq * 64 + g * 16) ^ ((rA & 7) << 4);
            bf16x8 A0 = *(const bf16x8*)(q + rA * 512 + inner);
            bf16x8 A1 = *(const bf16x8*)(q + (16 + rA) * 512 + inner);
            acc[0][0] = MFMA(A0, Freg[kq][0], acc[0][0]);
            acc[0][1] = MFMA(A0, Freg[kq][1], acc[0][1]);
            acc[1][0] = MFMA(A1, Freg[kq][0], acc[1][0]);
            acc[1][1] = MFMA(A1, Freg[kq][1], acc[1][1]);
        }
        float P0 = 0.f, P1 = 0.f;
#pragma unroll
        for (int m = 0; m < 2; ++m)
#pragma unroll
            for (int r = 0; r < 4; ++r) {
                P0 = fmaf(Wreg[m][0][r], acc[m][0][r], P0);
                P1 = fmaf(Wreg[m][1][r], acc[m][1][r], P1);
            }
        P0 += __shfl_xor(P0, 16); P0 += __shfl_xor(P0, 32);
        P1 += __shfl_xor(P1, 16); P1 += __shfl_xor(P1, 32);
        if (g == 0) {
            const int c0 = 32 * w + rA, c1 = c0 + 16;
            X[ia][c0 ^ ((ia & 7) << 3)] = f2bf(P0);
            X[ia][c1 ^ ((ia & 7) << 3)] = f2bf(P1);
        }
    }
    __syncthreads();

    // ---- mlp1: A = X (LDS), B = W1t (global), H -> LDS ----
    {
        f32x4 acc[2] = {};
#pragma unroll
        for (int k0 = 0; k0 < 8; ++k0) {
            const int ke = (k0 * 32 + 8 * g);
            bf16x8 A = *(const bf16x8*)(&X[rA][ke ^ ((rA & 7) << 3)]);
#pragma unroll
            for (int nt = 0; nt < 2; ++nt) {
                const int col = 32 * w + 16 * nt + rA;
                bf16x8 Bv = *(const bf16x8*)(W1t + (size_t)col * 256 + (ke ^ ((col & 7) << 3)));
                acc[nt] = MFMA(A, Bv, acc[nt]);
            }
        }
#pragma unroll
        for (int nt = 0; nt < 2; ++nt)
#pragma unroll
            for (int r = 0; r < 4; ++r) {
                const int row = 4 * g + r;
                const int col = 32 * w + 16 * nt + rA;
                float v = acc[nt][r] + b1[col];
                v = (v > 0.f) ? v : 0.01f * v;
                H[row][col ^ ((row & 7) << 3)] = f2bf(v);
            }
        // second 128 cols (4 waves x 32 cols per pass)
        f32x4 acc2[2] = {};
#pragma unroll
        for (int k0 = 0; k0 < 8; ++k0) {
            const int ke = (k0 * 32 + 8 * g);
            bf16x8 A = *(const bf16x8*)(&X[rA][ke ^ ((rA & 7) << 3)]);
#pragma unroll
            for (int nt = 0; nt < 2; ++nt) {
                const int col = 128 + 32 * w + 16 * nt + rA;
                bf16x8 Bv = *(const bf16x8*)(W1t + (size_t)col * 256 + (ke ^ ((col & 7) << 3)));
                acc2[nt] = MFMA(A, Bv, acc2[nt]);
            }
        }
#pragma unroll
        for (int nt = 0; nt < 2; ++nt)
#pragma unroll
            for (int r = 0; r < 4; ++r) {
                const int row = 4 * g + r;
                const int col = 128 + 32 * w + 16 * nt + rA;
                float v = acc2[nt][r] + b1[col];
                v = (v > 0.f) ? v : 0.01f * v;
                H[row][col ^ ((row & 7) << 3)] = f2bf(v);
            }
    }
    __syncthreads();

    // ---- mlp2: A = H (LDS), B = W2t (global), store out (2 valid rows) ----
#pragma unroll
    for (int half = 0; half < 2; ++half) {
        f32x4 acc[2] = {};
#pragma unroll
        for (int k0 = 0; k0 < 8; ++k0) {
            const int ke = (k0 * 32 + 8 * g);
            bf16x8 A = *(const bf16x8*)(&H[rA][ke ^ ((rA & 7) << 3)]);
#pragma unroll
            for (int nt = 0; nt < 2; ++nt) {
                const int col = 128 * half + 32 * w + 16 * nt + rA;
                bf16x8 Bv = *(const bf16x8*)(W2t + (size_t)col * 256 + (ke ^ ((col & 7) << 3)));
                acc[nt] = MFMA(A, Bv, acc[nt]);
            }
        }
#pragma unroll
        for (int nt = 0; nt < 2; ++nt)
#pragma unroll
            for (int r = 0; r < 4; ++r) {
                const int row = 4 * g + r;
                if (row < 2) {
                    const int col = 128 * half + 32 * w + 16 * nt + rA;
                    out[(size_t)(b * NN + r0 + row) * 256 + col] = acc[nt][r] + b2[col];
                }
            }
    }
}

extern "C" void kernel_launch(void* const* d_in, const int* in_sizes, int n_in,
                              void* d_out, int out_size, void* d_ws, size_t ws_size,
                              hipStream_t stream) {
    const float* features = (const float*)d_in[0];
    const float* norms    = (const float*)d_in[4];
    const float* rad_W    = (const float*)d_in[5];
    const float* rad_b    = (const float*)d_in[6];
    const float* W1       = (const float*)d_in[7];
    const float* b1       = (const float*)d_in[8];
    const float* W2       = (const float*)d_in[9];
    const float* b2       = (const float*)d_in[10];

    char* ws = (char*)d_ws;
    u16* Ft  = (u16*)ws;                  // 512 KB
    u16* W1t = (u16*)(ws + 524288);       // 128 KB
    u16* W2t = (u16*)(ws + 524288 + 131072);

    prep_kernel<<<96, 256, 0, stream>>>(features, W1, W2, Ft, W1t, W2t);
    fused_kernel<<<1024, 256, 0, stream>>>(norms, features, Ft, rad_W, rad_b,
                                           W1t, b1, W2t, b2, (float*)d_out);
}